// Round 6
// baseline (43.772 us; speedup 1.0000x reference)
//
#include <hip/hip_runtime.h>
#include <math.h>

#define OUT 14
#define RATIO 2
#define NS (OUT*RATIO)      // 28 sample positions per axis
#define NPIX (OUT*OUT)      // 196
#define C_TOT 256
#define CG 4                // channels per group (float4 interleave)
#define GPB 4               // groups per block (software pipeline depth)
#define NCHUNK (C_TOT/(CG*GPB))   // 16
#define NBOX_PER_B 128
#define NTHREADS 256
#define PATCH_CAP 1280      // float4 slots; worst-case patch ~1100
#define MAXIT 5             // ceil(PATCH_CAP/NTHREADS)
#define NROI 256

// ---- workspace layout ----
#define META_INTS 8
#define META_OFF  0
#define IDX_OFF   (NROI*META_INTS*4)                 // int4 [256][196]
#define WY_OFF    (IDX_OFF + NROI*NPIX*16)           // float4 [256][196]
#define WX_OFF    (WY_OFF  + NROI*NPIX*16)           // float4 [256][196]
#define WS_NEEDED (WX_OFF  + NROI*NPIX*16)           // ~2.42 MB

// =====================================================================
// Setup kernel: one block per roi. Computes level/meta + per-pixel tap
// records (indices + separable weights, 0.25 avg factor folded into y).
// =====================================================================
__global__ __launch_bounds__(NTHREADS)
void roi_setup_kernel(const float* __restrict__ boxes,
                      int*    __restrict__ metaW,
                      int4*   __restrict__ idxW,
                      float4* __restrict__ wyW,
                      float4* __restrict__ wxW)
{
    const int k   = blockIdx.x;
    const int tid = threadIdx.x;

    __shared__ int   s_ylo[NS], s_xlo[NS];
    __shared__ float s_fyh[NS], s_fyl[NS], s_fxh[NS], s_fxl[NS];

    const float bx1 = boxes[k*4+0];
    const float by1 = boxes[k*4+1];
    const float bx2 = boxes[k*4+2];
    const float by2 = boxes[k*4+3];

    const float wbox = bx2 - bx1;
    const float hbox = by2 - by1;
    const float sdim = sqrtf(wbox * hbox);
    float lvlf = floorf(4.0f + log2f(sdim / 224.0f + 1e-6f));
    lvlf = fminf(fmaxf(lvlf, 2.0f), 5.0f);
    const int lidx = (int)lvlf - 2;   // 0..3

    int H, W;
    float scale;
    if      (lidx == 0) { H = 200; W = 200; scale = 0.25f;    }
    else if (lidx == 1) { H = 100; W = 100; scale = 0.125f;   }
    else if (lidx == 2) { H = 50;  W = 50;  scale = 0.0625f;  }
    else                { H = 25;  W = 25;  scale = 0.03125f; }

    const float x1 = bx1 * scale;
    const float y1 = by1 * scale;
    const float x2 = bx2 * scale;
    const float y2 = by2 * scale;
    const float rw = fmaxf(x2 - x1, 1.0f);
    const float rh = fmaxf(y2 - y1, 1.0f);
    const float bw = rw / (float)OUT;
    const float bh = rh / (float)OUT;

    if (tid < NS) {
        const int i = tid;
        const float off = ((float)i + 0.5f) / (float)RATIO;
        {
            const float c  = y1 + bh * off;
            const bool  v  = (c > -1.0f) && (c < (float)H);
            const float cc = fminf(fmaxf(c, 0.0f), (float)(H - 1));
            const float fl = fminf(fmaxf(floorf(cc), 0.0f), (float)(H - 2));
            const float fr = cc - fl;
            s_ylo[i] = (int)fl;
            s_fyl[i] = v ? fr         : 0.0f;
            s_fyh[i] = v ? 1.0f - fr  : 0.0f;
        }
        {
            const float c  = x1 + bw * off;
            const bool  v  = (c > -1.0f) && (c < (float)W);
            const float cc = fminf(fmaxf(c, 0.0f), (float)(W - 1));
            const float fl = fminf(fmaxf(floorf(cc), 0.0f), (float)(W - 2));
            const float fr = cc - fl;
            s_xlo[i] = (int)fl;
            s_fxl[i] = v ? fr         : 0.0f;
            s_fxh[i] = v ? 1.0f - fr  : 0.0f;
        }
    }
    __syncthreads();

    const int ymin  = s_ylo[0];
    const int xmin  = s_xlo[0];
    const int nrows = s_ylo[NS-1] + 2 - ymin;
    const int ncols = s_xlo[NS-1] + 2 - xmin;
    const int padded  = ncols | 1;
    const int stridep = (nrows * padded <= PATCH_CAP) ? padded : ncols;

    if (tid == 0) {
        int* m = metaW + k*META_INTS;
        m[0] = lidx;
        m[1] = ymin;
        m[2] = xmin;
        m[3] = nrows;
        m[4] = ncols;
        m[5] = stridep;
        m[6] = nrows * ncols;
        m[7] = __float_as_int(1.0f / (float)ncols);
    }

    if (tid < NPIX) {
        const int ph = tid / OUT;
        const int pw = tid - ph * OUT;
        const int sy0 = 2*ph, sy1 = 2*ph + 1;
        const int sx0 = 2*pw, sx1 = 2*pw + 1;
        int4 iv;
        iv.x = (s_ylo[sy0] - ymin) * stridep;   // row base 0
        iv.y = (s_ylo[sy1] - ymin) * stridep;   // row base 1
        iv.z =  s_xlo[sx0] - xmin;              // col base 0
        iv.w =  s_xlo[sx1] - xmin;              // col base 1
        idxW[k*NPIX + tid] = iv;
        float4 wy;   // 0.25 sample-average folded into y weights
        wy.x = s_fyh[sy0] * 0.25f;
        wy.y = s_fyl[sy0] * 0.25f;
        wy.z = s_fyh[sy1] * 0.25f;
        wy.w = s_fyl[sy1] * 0.25f;
        float4 wx;
        wx.x = s_fxh[sx0];
        wx.y = s_fxl[sx0];
        wx.z = s_fxh[sx1];
        wx.w = s_fxl[sx1];
        wyW[k*NPIX + tid] = wy;
        wxW[k*NPIX + tid] = wx;
    }
}

// =====================================================================
// Pipelined main kernel: grid (16 chunks, 256 rois); each block handles
// GPB=4 channel-groups of one roi. Per iteration:
//   ds_write staged regs -> issue next group's global loads -> barrier
//   -> compute current group -> barrier.
// Next group's HBM latency hides under current group's compute.
// Staging coords (go_/di_) are group-independent: computed once.
// =====================================================================
__global__ __launch_bounds__(NTHREADS)
void roi_align_pipe_kernel(const float* __restrict__ f0,
                           const float* __restrict__ f1,
                           const float* __restrict__ f2,
                           const float* __restrict__ f3,
                           const int*    __restrict__ metaW,
                           const int4*   __restrict__ idxW,
                           const float4* __restrict__ wyW,
                           const float4* __restrict__ wxW,
                           float* __restrict__ out)
{
    const int chunk = blockIdx.x;   // 0..15
    const int k     = blockIdx.y;   // roi, 0..255
    const int tid   = threadIdx.x;

    __shared__ float4 s_patch[PATCH_CAP];   // 20480 B

    // ---- per-pixel records (loaded once, reused for all GPB groups) ----
    const bool active = (tid < NPIX);
    int4   iv = {0,0,0,0};
    float4 wy = {0,0,0,0};
    float4 wx = {0,0,0,0};
    if (active) {
        iv = idxW[k*NPIX + tid];
        wy = wyW[k*NPIX + tid];
        wx = wxW[k*NPIX + tid];
    }

    // ---- uniform meta (scalar loads) ----
    const int* m = metaW + k*META_INTS;
    const int lidx    = m[0];
    const int ymin    = m[1];
    const int xmin    = m[2];
    const int ncols   = m[4];
    const int stridep = m[5];
    const int nelem   = m[6];
    const float rcpc  = __int_as_float(m[7]);

    const float* fptr;
    int W;
    if      (lidx == 0) { fptr = f0; W = 200; }
    else if (lidx == 1) { fptr = f1; W = 100; }
    else if (lidx == 2) { fptr = f2; W = 50;  }
    else                { fptr = f3; W = 25;  }
    const size_t plane = (size_t)W * (size_t)W;

    const float* fbase = fptr
        + ((size_t)(k / NBOX_PER_B) * C_TOT + (size_t)chunk * (GPB*CG)) * plane
        + (size_t)ymin * W + xmin;

    // ---- per-thread staging coordinates (group-independent) ----
    int go_[MAXIT], di_[MAXIT];
    #pragma unroll
    for (int t = 0; t < MAXIT; ++t) {
        const int i  = t*NTHREADS + tid;
        const int r  = (int)(((float)i + 0.5f) * rcpc);   // exact floor (margin >> err)
        const int cc = i - r * ncols;
        go_[t] = r * W + cc;
        di_[t] = (i < nelem) ? (r * stridep + cc) : -1;
    }

    // ---- prologue: issue group 0 loads into regs ----
    float4 sv[MAXIT];
    {
        const float* g0 = fbase;
        #pragma unroll
        for (int t = 0; t < MAXIT; ++t) {
            if (di_[t] >= 0) {
                const int go = go_[t];
                sv[t].x = g0[go];
                sv[t].y = g0[go +   plane];
                sv[t].z = g0[go + 2*plane];
                sv[t].w = g0[go + 3*plane];
            }
        }
    }

    #pragma unroll
    for (int g = 0; g < GPB; ++g) {
        // ---- commit staged regs to LDS ----
        #pragma unroll
        for (int t = 0; t < MAXIT; ++t)
            if (di_[t] >= 0) s_patch[di_[t]] = sv[t];

        // ---- issue NEXT group's loads (latency hides under compute) ----
        if (g + 1 < GPB) {
            const float* gN = fbase + (size_t)((g+1)*CG) * plane;
            #pragma unroll
            for (int t = 0; t < MAXIT; ++t) {
                if (di_[t] >= 0) {
                    const int go = go_[t];
                    sv[t].x = gN[go];
                    sv[t].y = gN[go +   plane];
                    sv[t].z = gN[go + 2*plane];
                    sv[t].w = gN[go + 3*plane];
                }
            }
        }
        __syncthreads();

        // ---- bilinear: 16 x ds_read_b128, 64 FMA (4 channels) ----
        if (active) {
            float4 acc = {0.0f, 0.0f, 0.0f, 0.0f};
            #pragma unroll
            for (int ys = 0; ys < 2; ++ys) {
                const int   rb = ys ? iv.y : iv.x;
                const float yh = ys ? wy.z : wy.x;
                const float yl = ys ? wy.w : wy.y;
                #pragma unroll
                for (int xs = 0; xs < 2; ++xs) {
                    const int base = rb + (xs ? iv.w : iv.z);
                    const float xh = xs ? wx.z : wx.x;
                    const float xl = xs ? wx.w : wx.y;
                    const float w00 = yh*xh, w01 = yh*xl, w10 = yl*xh, w11 = yl*xl;
                    const float4 v00 = s_patch[base];
                    const float4 v01 = s_patch[base + 1];
                    const float4 v10 = s_patch[base + stridep];
                    const float4 v11 = s_patch[base + stridep + 1];
                    acc.x += w00*v00.x + w01*v01.x + w10*v10.x + w11*v11.x;
                    acc.y += w00*v00.y + w01*v01.y + w10*v10.y + w11*v11.y;
                    acc.z += w00*v00.z + w01*v01.z + w10*v10.z + w11*v11.z;
                    acc.w += w00*v00.w + w01*v01.w + w10*v10.w + w11*v11.w;
                }
            }
            float* ob = out + ((size_t)k * C_TOT + (size_t)(chunk*GPB + g) * CG) * NPIX + tid;
            ob[0*NPIX] = acc.x;
            ob[1*NPIX] = acc.y;
            ob[2*NPIX] = acc.z;
            ob[3*NPIX] = acc.w;
        }
        __syncthreads();
    }
}

// =====================================================================
// Fallback: proven R4 monolithic kernel (used only if ws too small)
// =====================================================================
__global__ __launch_bounds__(NTHREADS)
void roi_align_fpn_kernel(const float* __restrict__ f0,
                          const float* __restrict__ f1,
                          const float* __restrict__ f2,
                          const float* __restrict__ f3,
                          const float* __restrict__ boxes,
                          float* __restrict__ out)
{
    const int k   = blockIdx.x;
    const int cg  = blockIdx.y;
    const int tid = threadIdx.x;

    __shared__ float4 s_patch[PATCH_CAP];
    __shared__ int   s_ylo[NS], s_xlo[NS];
    __shared__ float s_fyh[NS], s_fyl[NS], s_fxh[NS], s_fxl[NS];

    const float bx1 = boxes[k*4+0];
    const float by1 = boxes[k*4+1];
    const float bx2 = boxes[k*4+2];
    const float by2 = boxes[k*4+3];

    const float wbox = bx2 - bx1;
    const float hbox = by2 - by1;
    const float sdim = sqrtf(wbox * hbox);
    float lvlf = floorf(4.0f + log2f(sdim / 224.0f + 1e-6f));
    lvlf = fminf(fmaxf(lvlf, 2.0f), 5.0f);
    const int lidx = (int)lvlf - 2;

    const float* fptr;
    int H, W;
    float scale;
    if      (lidx == 0) { fptr = f0; H = 200; W = 200; scale = 0.25f;    }
    else if (lidx == 1) { fptr = f1; H = 100; W = 100; scale = 0.125f;   }
    else if (lidx == 2) { fptr = f2; H = 50;  W = 50;  scale = 0.0625f;  }
    else                { fptr = f3; H = 25;  W = 25;  scale = 0.03125f; }

    const float x1 = bx1 * scale;
    const float y1 = by1 * scale;
    const float x2 = bx2 * scale;
    const float y2 = by2 * scale;
    const float rw = fmaxf(x2 - x1, 1.0f);
    const float rh = fmaxf(y2 - y1, 1.0f);
    const float bw = rw / (float)OUT;
    const float bh = rh / (float)OUT;

    if (tid < NS) {
        const int i = tid;
        const float off = ((float)i + 0.5f) / (float)RATIO;
        {
            const float c  = y1 + bh * off;
            const bool  v  = (c > -1.0f) && (c < (float)H);
            const float cc = fminf(fmaxf(c, 0.0f), (float)(H - 1));
            const float fl = fminf(fmaxf(floorf(cc), 0.0f), (float)(H - 2));
            const float fr = cc - fl;
            s_ylo[i] = (int)fl;
            s_fyl[i] = v ? fr         : 0.0f;
            s_fyh[i] = v ? 1.0f - fr  : 0.0f;
        }
        {
            const float c  = x1 + bw * off;
            const bool  v  = (c > -1.0f) && (c < (float)W);
            const float cc = fminf(fmaxf(c, 0.0f), (float)(W - 1));
            const float fl = fminf(fmaxf(floorf(cc), 0.0f), (float)(W - 2));
            const float fr = cc - fl;
            s_xlo[i] = (int)fl;
            s_fxl[i] = v ? fr         : 0.0f;
            s_fxh[i] = v ? 1.0f - fr  : 0.0f;
        }
    }
    __syncthreads();

    const int ymin  = s_ylo[0];
    const int xmin  = s_xlo[0];
    const int nrows = s_ylo[NS-1] + 2 - ymin;
    const int ncols = s_xlo[NS-1] + 2 - xmin;
    const int padded = ncols | 1;
    const int stridep = (nrows * padded <= PATCH_CAP) ? padded : ncols;
    const int nelem = nrows * ncols;
    const float rcpc = 1.0f / (float)ncols;

    const bool active = (tid < NPIX);
    int rb0 = 0, rb1 = 0, cbase0 = 0, cbase1 = 0;
    float wt[16];
    #pragma unroll
    for (int i = 0; i < 16; ++i) wt[i] = 0.0f;
    if (active) {
        const int ph = tid / OUT;
        const int pw = tid - ph * OUT;
        const int sy0 = 2*ph, sy1 = 2*ph + 1;
        const int sx0 = 2*pw, sx1 = 2*pw + 1;
        rb0 = (s_ylo[sy0] - ymin) * stridep;
        rb1 = (s_ylo[sy1] - ymin) * stridep;
        cbase0 = s_xlo[sx0] - xmin;
        cbase1 = s_xlo[sx1] - xmin;
        const float fyh_[2] = { s_fyh[sy0], s_fyh[sy1] };
        const float fyl_[2] = { s_fyl[sy0], s_fyl[sy1] };
        const float fxh_[2] = { s_fxh[sx0], s_fxh[sx1] };
        const float fxl_[2] = { s_fxl[sx0], s_fxl[sx1] };
        #pragma unroll
        for (int ys = 0; ys < 2; ++ys) {
            #pragma unroll
            for (int xs = 0; xs < 2; ++xs) {
                const int o = (ys*2 + xs) * 4;
                wt[o+0] = fyh_[ys] * fxh_[xs] * 0.25f;
                wt[o+1] = fyh_[ys] * fxl_[xs] * 0.25f;
                wt[o+2] = fyl_[ys] * fxh_[xs] * 0.25f;
                wt[o+3] = fyl_[ys] * fxl_[xs] * 0.25f;
            }
        }
    }

    const int bidx = k / NBOX_PER_B;
    const size_t plane = (size_t)H * (size_t)W;
    const float* fbase = fptr + ((size_t)bidx * C_TOT + (size_t)cg * CG) * plane
                              + (size_t)ymin * W + xmin;
    const float* g0 = fbase;
    const float* g1 = fbase + plane;
    const float* g2 = fbase + 2*plane;
    const float* g3 = fbase + 3*plane;
    for (int i = tid; i < nelem; i += NTHREADS) {
        const int r  = (int)(((float)i + 0.5f) * rcpc);
        const int cc = i - r * ncols;
        const int go = r * W + cc;
        const int di = r * stridep + cc;
        float4 v;
        v.x = g0[go]; v.y = g1[go]; v.z = g2[go]; v.w = g3[go];
        if (di < PATCH_CAP) s_patch[di] = v;
    }
    __syncthreads();

    if (active) {
        float4 acc = {0.0f, 0.0f, 0.0f, 0.0f};
        #pragma unroll
        for (int ys = 0; ys < 2; ++ys) {
            const int rbase = (ys == 0) ? rb0 : rb1;
            #pragma unroll
            for (int xs = 0; xs < 2; ++xs) {
                const int base = rbase + ((xs == 0) ? cbase0 : cbase1);
                const float4 v00 = s_patch[base];
                const float4 v01 = s_patch[base + 1];
                const float4 v10 = s_patch[base + stridep];
                const float4 v11 = s_patch[base + stridep + 1];
                const int o = (ys*2 + xs) * 4;
                const float w00 = wt[o+0], w01 = wt[o+1], w10 = wt[o+2], w11 = wt[o+3];
                acc.x += w00*v00.x + w01*v01.x + w10*v10.x + w11*v11.x;
                acc.y += w00*v00.y + w01*v01.y + w10*v10.y + w11*v11.y;
                acc.z += w00*v00.z + w01*v01.z + w10*v10.z + w11*v11.z;
                acc.w += w00*v00.w + w01*v01.w + w10*v10.w + w11*v11.w;
            }
        }
        float* ob = out + ((size_t)k * C_TOT + (size_t)cg * CG) * NPIX + tid;
        ob[0*NPIX] = acc.x;
        ob[1*NPIX] = acc.y;
        ob[2*NPIX] = acc.z;
        ob[3*NPIX] = acc.w;
    }
}

extern "C" void kernel_launch(void* const* d_in, const int* in_sizes, int n_in,
                              void* d_out, int out_size, void* d_ws, size_t ws_size,
                              hipStream_t stream) {
    const float* f0    = (const float*)d_in[0];
    const float* f1    = (const float*)d_in[1];
    const float* f2    = (const float*)d_in[2];
    const float* f3    = (const float*)d_in[3];
    const float* boxes = (const float*)d_in[4];
    float* out = (float*)d_out;

    if (ws_size >= (size_t)WS_NEEDED) {
        char* ws = (char*)d_ws;
        int*    metaW = (int*)   (ws + META_OFF);
        int4*   idxW  = (int4*)  (ws + IDX_OFF);
        float4* wyW   = (float4*)(ws + WY_OFF);
        float4* wxW   = (float4*)(ws + WX_OFF);

        roi_setup_kernel<<<NROI, NTHREADS, 0, stream>>>(boxes, metaW, idxW, wyW, wxW);
        dim3 grid(NCHUNK, NROI);   // 16 chunks x 256 rois
        roi_align_pipe_kernel<<<grid, NTHREADS, 0, stream>>>(
            f0, f1, f2, f3, metaW, idxW, wyW, wxW, out);
    } else {
        dim3 grid(NROI, C_TOT / CG);
        roi_align_fpn_kernel<<<grid, NTHREADS, 0, stream>>>(f0, f1, f2, f3, boxes, out);
    }
}